// Round 12
// baseline (954.663 us; speedup 1.0000x reference)
//
#include <hip/hip_runtime.h>

#define KT 4
#define KN 20000        // NA == ND == 20000
#define KE 100000
#define KH 128
#define KL 2
#define KNT 40000       // NA + ND

typedef __attribute__((ext_vector_type(8))) short short8v;
typedef __attribute__((ext_vector_type(4))) float f32x4;

__device__ __forceinline__ short bf16rn(float x) {
    unsigned u = __float_as_uint(x);
    u = (u + 0x7fffu + ((u >> 16) & 1u)) >> 16;
    return (short)u;
}
__device__ __forceinline__ float bf16tof(short h) {
    return __uint_as_float(((unsigned)(unsigned short)h) << 16);
}

// ---------------------------------------------------------------------------
// W pre-split: wsp[((mat*2+h)*4 + kc)*4096 + col*32 + kk], k = kc*32+kk.
// mat = arr*8 + (t*2+l), arr: 0=w1_ad 1=w1_da 2=w2_ad 3=w2_da.
// ---------------------------------------------------------------------------
__global__ __launch_bounds__(256)
void wsplit_k(const float* __restrict__ w1_ad, const float* __restrict__ w1_da,
              const float* __restrict__ w2_ad, const float* __restrict__ w2_da,
              short* __restrict__ wsp) {
    int mat = blockIdx.x >> 3, part = blockIdx.x & 7;   // mat 0..31
    int arr = mat >> 3, rem = mat & 7;   // rem = t*2+l
    const float* src = (arr == 0 ? w1_ad : arr == 1 ? w1_da : arr == 2 ? w2_ad : w2_da)
                       + (long)rem * KH * KH;
    #pragma unroll
    for (int p = 0; p < 8; ++p) {
        int idx = part * 2048 + p * 256 + threadIdx.x;  // 16384 elems total
        int k = idx >> 7, c = idx & 127;
        float v = src[idx];
        short hi = bf16rn(v);
        short lo = bf16rn(v - bf16tof(hi));
        int chunk = k >> 5, kk = k & 31;
        long ohi = ((long)(mat * 2 + 0) * 4 + chunk) * 4096 + c * 32 + kk;
        long olo = ((long)(mat * 2 + 1) * 4 + chunk) * 4096 + c * 32 + kk;
        wsp[ohi] = hi;
        wsp[olo] = lo;
    }
}

// ---------------------------------------------------------------------------
// init_k: agg[z][n][:] = (1+eps) * x_dst[n][:]   (pure sequential stream)
// ---------------------------------------------------------------------------
__global__ __launch_bounds__(256)
void init_k(const float* __restrict__ xa, const float* __restrict__ xd,
            const float* __restrict__ out,
            const float* __restrict__ eps_ad, const float* __restrict__ eps_da,
            float* __restrict__ agg, int l) {
    int z = blockIdx.y, t = z >> 1, et = z & 1;
    const float* eps = et ? eps_da : eps_ad;
    float scale = 1.0f + eps[t * KL + l];
    const float* dstp;
    if (l == 0) dstp = et ? (xa + (long)t * KN * KH) : (xd + (long)t * KN * KH);
    else        dstp = out + (long)t * KNT * KH + (et ? 0 : (long)KN * KH);
    const float4* s4 = (const float4*)dstp;
    float4* a4 = (float4*)(agg + (long)z * KN * KH);
    int i = blockIdx.x * 256 + threadIdx.x;        // grid exact: KN*KH/4 units
    float4 v = s4[i];
    v.x *= scale; v.y *= scale; v.z *= scale; v.w *= scale;
    a4[i] = v;
}

// ---------------------------------------------------------------------------
// edge_k: one 32-lane group per edge, edges in ORIGINAL order.
//   ea row  : sequential fp32 stream (the big win: 410 MB at stream rate)
//   x_src   : row read, random row but small L2/L3-resident footprint
//   deposit : atomicAdd f32 into agg[dst] -- lane li owns feats {li,+32,+64,+96}
//             so each wave-atomic instruction covers a 128B-contiguous range
//             (2 cache lines) and HW coalesces same-line atomics.
// ---------------------------------------------------------------------------
__global__ __launch_bounds__(256)
void edge_k(const int* __restrict__ ei_ad, const int* __restrict__ ei_da,
            const float* __restrict__ ea_ad, const float* __restrict__ ea_da,
            const float* __restrict__ xa, const float* __restrict__ xd,
            const float* __restrict__ out,
            float* __restrict__ agg, int l) {
    int z = blockIdx.y, t = z >> 1, et = z & 1;
    int g = threadIdx.x >> 5, li = threadIdx.x & 31;
    int e = blockIdx.x * 8 + g;                     // grid exact: KE/8 blocks
    const int* ei = et ? ei_da : ei_ad;
    int srcn = ei[(t * 2 + 0) * KE + e];
    int dstn = ei[(t * 2 + 1) * KE + e];
    const float* xsrc;
    if (l == 0) xsrc = et ? (xd + (long)t * KN * KH) : (xa + (long)t * KN * KH);
    else        xsrc = out + (long)t * KNT * KH + (et ? (long)KN * KH : 0);
    const float* earow = (et ? ea_da : ea_ad) + ((long)t * KE + e) * KH;
    const float* xrow  = xsrc + (long)srcn * KH;
    float* arow = agg + ((long)z * KN + dstn) * KH;

    float e0 = earow[li], e1 = earow[li + 32], e2 = earow[li + 64], e3 = earow[li + 96];
    float x0 = xrow[li],  x1 = xrow[li + 32],  x2 = xrow[li + 64],  x3 = xrow[li + 96];
    atomicAdd(arow + li,      fmaxf(x0 + e0, 0.f));
    atomicAdd(arow + li + 32, fmaxf(x1 + e1, 0.f));
    atomicAdd(arow + li + 64, fmaxf(x2 + e2, 0.f));
    atomicAdd(arow + li + 96, fmaxf(x3 + e3, 0.f));
}

// ---------------------------------------------------------------------------
// Zero-LDS MFMA GEMM (3-term bf16-split): out = [relu](H @ W + b).
// INFMT 0: H read as fp32 agg, hi/lo split in-register (GEMM1).
// INFMT 1: H read as bf16 hi/lo mid buffers (GEMM2).
// mode 0: write bf16 hi/lo mid.  mode 1: write fp32 to d_out.
// Operand-swapped (W in A-slot) -> coalesced float4 epilogue.
// ---------------------------------------------------------------------------
template <int INFMT>
__global__ __launch_bounds__(256)
void gemm_k(const float* __restrict__ aggf,
            const short* __restrict__ mhi, const short* __restrict__ mlo,
            const short* __restrict__ wsp,
            const float* __restrict__ b_ad, const float* __restrict__ b_da,
            short* __restrict__ ohi, short* __restrict__ olo,
            float* __restrict__ d_out,
            int l, int which, int relu, int mode) {
    int z = blockIdx.y, t = z >> 1, et = z & 1;
    int tid = threadIdx.x;
    int mat = (which * 2 + et) * 8 + t * 2 + l;
    const float* Bp = (et ? b_da : b_ad) + (long)(t * KL + l) * KH;
    int r0 = blockIdx.x * 128;

    int lane = tid & 63, wid = tid >> 6;
    int wr = wid >> 1, wc = wid & 1;
    int lrow = lane & 15, lq = lane >> 4;

    f32x4 acc[4][4];
    #pragma unroll
    for (int i = 0; i < 4; ++i)
        #pragma unroll
        for (int j = 0; j < 4; ++j) acc[i][j] = (f32x4){0.f, 0.f, 0.f, 0.f};

    #pragma unroll
    for (int kc = 0; kc < 4; ++kc) {
        const short* whp = wsp + ((long)(mat * 2 + 0) * 4 + kc) * 4096;
        const short* wlp = wsp + ((long)(mat * 2 + 1) * 4 + kc) * 4096;
        short8v bhi[4], blo[4];
        #pragma unroll
        for (int j = 0; j < 4; ++j) {
            int off = (wc * 64 + j * 16 + lrow) * 32 + lq * 8;
            bhi[j] = *(const short8v*)(whp + off);
            blo[j] = *(const short8v*)(wlp + off);
        }
        #pragma unroll
        for (int i = 0; i < 4; ++i) {
            int row = min(r0 + wr * 64 + i * 16 + lrow, KN - 1);
            long o = (long)row * KH + kc * 32 + lq * 8;
            short8v ahi, alo;
            if (INFMT == 0) {
                const float* p = aggf + (long)z * KN * KH + o;
                float4 va = *(const float4*)p;
                float4 vb = *(const float4*)(p + 4);
                float vv[8] = {va.x, va.y, va.z, va.w, vb.x, vb.y, vb.z, vb.w};
                #pragma unroll
                for (int q = 0; q < 8; ++q) {
                    short h = bf16rn(vv[q]);
                    ahi[q] = h;
                    alo[q] = bf16rn(vv[q] - bf16tof(h));
                }
            } else {
                ahi = *(const short8v*)(mhi + (long)z * KN * KH + o);
                alo = *(const short8v*)(mlo + (long)z * KN * KH + o);
            }
            #pragma unroll
            for (int j = 0; j < 4; ++j) {
                acc[i][j] = __builtin_amdgcn_mfma_f32_16x16x32_bf16(bhi[j], ahi, acc[i][j], 0, 0, 0);
                acc[i][j] = __builtin_amdgcn_mfma_f32_16x16x32_bf16(blo[j], ahi, acc[i][j], 0, 0, 0);
                acc[i][j] = __builtin_amdgcn_mfma_f32_16x16x32_bf16(bhi[j], alo, acc[i][j], 0, 0, 0);
            }
        }
    }

    // ---- epilogue: lane holds cols (wc*64+j*16+lq*4 .. +3) of node
    //      (r0+wr*64+i*16+lrow) -> coalesced stores ----
    #pragma unroll
    for (int i = 0; i < 4; ++i) {
        int node = r0 + wr * 64 + i * 16 + lrow;
        if (node >= KN) continue;
        #pragma unroll
        for (int j = 0; j < 4; ++j) {
            int col = wc * 64 + j * 16 + lq * 4;
            float4 b4 = *(const float4*)&Bp[col];
            f32x4 a = acc[i][j];
            float4 v;
            v.x = a[0] + b4.x; v.y = a[1] + b4.y;
            v.z = a[2] + b4.z; v.w = a[3] + b4.w;
            if (relu) {
                v.x = fmaxf(v.x, 0.f); v.y = fmaxf(v.y, 0.f);
                v.z = fmaxf(v.z, 0.f); v.w = fmaxf(v.w, 0.f);
            }
            if (mode == 0) {
                unsigned short h0 = (unsigned short)bf16rn(v.x);
                unsigned short h1 = (unsigned short)bf16rn(v.y);
                unsigned short h2 = (unsigned short)bf16rn(v.z);
                unsigned short h3 = (unsigned short)bf16rn(v.w);
                unsigned short q0 = (unsigned short)bf16rn(v.x - bf16tof((short)h0));
                unsigned short q1 = (unsigned short)bf16rn(v.y - bf16tof((short)h1));
                unsigned short q2 = (unsigned short)bf16rn(v.z - bf16tof((short)h2));
                unsigned short q3 = (unsigned short)bf16rn(v.w - bf16tof((short)h3));
                long o = ((long)z * KN + node) * KH + col;
                *(uint2*)(ohi + o) = make_uint2(((unsigned)h1 << 16) | h0,
                                                ((unsigned)h3 << 16) | h2);
                *(uint2*)(olo + o) = make_uint2(((unsigned)q1 << 16) | q0,
                                                ((unsigned)q3 << 16) | q2);
            } else {
                long off = (long)t * KNT * KH + (et == 0 ? (long)KN * KH : 0)
                         + (long)node * KH + col;
                *(float4*)&d_out[off] = v;
            }
        }
    }
}

// ---------------------------------------------------------------------------
extern "C" void kernel_launch(void* const* d_in, const int* in_sizes, int n_in,
                              void* d_out_v, int out_size, void* d_ws, size_t ws_size,
                              hipStream_t stream) {
    const float* x_a    = (const float*)d_in[0];
    const float* x_d    = (const float*)d_in[1];
    const float* ea_ad  = (const float*)d_in[2];
    const float* ea_da  = (const float*)d_in[3];
    const int*   ei_ad  = (const int*)d_in[4];
    const int*   ei_da  = (const int*)d_in[5];
    const float* w1_ad  = (const float*)d_in[6];
    const float* b1_ad  = (const float*)d_in[7];
    const float* w2_ad  = (const float*)d_in[8];
    const float* b2_ad  = (const float*)d_in[9];
    const float* eps_ad = (const float*)d_in[10];
    const float* w1_da  = (const float*)d_in[11];
    const float* b1_da  = (const float*)d_in[12];
    const float* w2_da  = (const float*)d_in[13];
    const float* b2_da  = (const float*)d_in[14];
    const float* eps_da = (const float*)d_in[15];
    float* out = (float*)d_out_v;

    // workspace layout: agg fp32 | mid_hi | mid_lo | wsp   (~166 MB)
    size_t nEl = (size_t)8 * KN * KH;             // 20.48M elements
    float* agg = (float*)d_ws;
    short* mhi = (short*)(agg + nEl);
    short* mlo = mhi + nEl;
    short* wsp = mlo + nEl;                       // 1,048,576 shorts

    wsplit_k<<<256, 256, 0, stream>>>(w1_ad, w1_da, w2_ad, w2_da, wsp);

    dim3 ig(KN * KH / 4 / 256, 8);   // 2500 x 8, exact
    dim3 eg(KE / 8, 8);              // 12500 x 8, exact
    dim3 gg((KN + 127) / 128, 8);    // 157 x 8

    for (int l = 0; l < KL; ++l) {
        init_k<<<ig, 256, 0, stream>>>(x_a, x_d, out, eps_ad, eps_da, agg, l);
        edge_k<<<eg, 256, 0, stream>>>(ei_ad, ei_da, ea_ad, ea_da,
                                       x_a, x_d, out, agg, l);
        // mid = relu(agg @ w1 + b1): fp32 in, bf16 hi/lo out
        gemm_k<0><<<gg, 256, 0, stream>>>(agg, mhi, mlo, wsp, b1_ad, b1_da,
                                          mhi, mlo, out, l, 0, 1, 0);
        // x_new = mid @ w2 + b2 (+relu between layers) -> d_out fp32
        gemm_k<1><<<gg, 256, 0, stream>>>(agg, mhi, mlo, wsp, b2_ad, b2_da,
                                          mhi, mlo, out, l, 1, (l == 0) ? 1 : 0, 1);
    }
}

// Round 13
// 577.036 us; speedup vs baseline: 1.6544x; 1.6544x over previous
//
#include <hip/hip_runtime.h>

#define KT 4
#define KN 20000        // NA == ND == 20000
#define KE 100000
#define KH 128
#define KL 2
#define KNT 40000       // NA + ND

typedef __attribute__((ext_vector_type(8))) short short8v;
typedef __attribute__((ext_vector_type(4))) float f32x4;

__device__ __forceinline__ short bf16rn(float x) {
    unsigned u = __float_as_uint(x);
    u = (u + 0x7fffu + ((u >> 16) & 1u)) >> 16;
    return (short)u;
}
__device__ __forceinline__ float bf16tof(short h) {
    return __uint_as_float(((unsigned)(unsigned short)h) << 16);
}
__device__ __forceinline__ short8v mk8(uint2 a, uint2 b) {
    union { unsigned u[4]; short8v s; } c;
    c.u[0] = a.x; c.u[1] = a.y; c.u[2] = b.x; c.u[3] = b.y;
    return c.s;
}

// ---------------------------------------------------------------------------
// CSR build: counts -> scan -> fill (packed (edge, src) pairs).
// ---------------------------------------------------------------------------
__global__ void count_k(const int* __restrict__ ei_ad, const int* __restrict__ ei_da,
                        int* __restrict__ cnt) {
    int e = blockIdx.x * 256 + threadIdx.x;
    int z = blockIdx.y;                 // z = t*2 + et
    if (e >= KE) return;
    int t = z >> 1, et = z & 1;
    const int* ei = et ? ei_da : ei_ad;
    int dst = ei[(t * 2 + 1) * KE + e];
    atomicAdd(&cnt[z * KN + dst], 1);
}

__global__ void scan_k(int* __restrict__ cnt, int* __restrict__ offs) {
    __shared__ int s[256];
    int z = blockIdx.x, tid = threadIdx.x;
    const int CH = (KN + 255) / 256;    // 79
    int n0 = tid * CH;
    int lim = n0 < KN ? min(CH, KN - n0) : 0;
    long base = (long)z * KN + n0;
    int sum = 0;
    for (int i = 0; i < lim; ++i) sum += cnt[base + i];
    s[tid] = sum;
    __syncthreads();
    for (int off = 1; off < 256; off <<= 1) {
        int v = (tid >= off) ? s[tid - off] : 0;
        __syncthreads();
        s[tid] += v;
        __syncthreads();
    }
    int run = s[tid] - sum;             // exclusive prefix
    for (int i = 0; i < lim; ++i) {
        int c = cnt[base + i];
        offs[(long)z * (KN + 1) + n0 + i] = run;
        cnt[base + i] = run;            // becomes fill cursor
        run += c;
    }
    if (tid == 0) offs[(long)z * (KN + 1) + KN] = KE;
}

__global__ void fill_k(const int* __restrict__ ei_ad, const int* __restrict__ ei_da,
                       int* __restrict__ cur, int2* __restrict__ pes) {
    int e = blockIdx.x * 256 + threadIdx.x;
    int z = blockIdx.y;
    if (e >= KE) return;
    int t = z >> 1, et = z & 1;
    const int* ei = et ? ei_da : ei_ad;
    int src = ei[(t * 2 + 0) * KE + e];
    int dst = ei[(t * 2 + 1) * KE + e];
    int pos = atomicAdd(&cur[z * KN + dst], 1);
    pes[(long)z * KE + pos] = make_int2(e, src);
}

// ---------------------------------------------------------------------------
// Aggregation: 32-lane group per node (8 nodes/block), 4-deep clamped batch
// of fp32 row gathers (ea + x_src), mask-predicated accumulate.  Output
// written pre-split bf16 hi/lo for the fused MLP kernel.  (Proven loop from
// R11; ~3 TB/s mixed-random ceiling — structural floor for this phase.)
// ---------------------------------------------------------------------------
__global__ __launch_bounds__(256)
void agg_k(const float* __restrict__ xa_base, long xa_ts,
           const float* __restrict__ xd_base, long xd_ts,
           const float* __restrict__ ea_ad, const float* __restrict__ ea_da,
           const float* __restrict__ eps_ad, const float* __restrict__ eps_da,
           const int* __restrict__ offs, const int2* __restrict__ pes,
           short* __restrict__ agg_hi, short* __restrict__ agg_lo, int l) {
    int z = blockIdx.y, t = z >> 1, et = z & 1;
    int li = threadIdx.x & 31;
    int node = blockIdx.x * 8 + (threadIdx.x >> 5);   // grid exact: KN/8

    const float* ea  = (et ? ea_da : ea_ad) + (long)t * KE * KH;
    const float* eps = et ? eps_da : eps_ad;
    const float* src = et ? (xd_base + t * xd_ts) : (xa_base + t * xa_ts);
    const float* dst = et ? (xa_base + t * xa_ts) : (xd_base + t * xd_ts);
    const int2*  pz  = pes + (long)z * KE;

    int beg = offs[(long)z * (KN + 1) + node];
    int end = offs[(long)z * (KN + 1) + node + 1];
    float scale = 1.0f + eps[t * KL + l];

    float4 dv = *(const float4*)(dst + (long)node * KH + li * 4);
    float4 acc = make_float4(0.f, 0.f, 0.f, 0.f);

    if (beg < end) {
        int last = end - 1;
        for (int i = beg; i < end; i += 4) {
            int i0 = min(i, last), i1 = min(i + 1, last),
                i2 = min(i + 2, last), i3 = min(i + 3, last);
            int2 p0 = pz[i0], p1 = pz[i1], p2 = pz[i2], p3 = pz[i3];
            float4 e0 = *(const float4*)(ea + (long)p0.x * KH + li * 4);
            float4 e1 = *(const float4*)(ea + (long)p1.x * KH + li * 4);
            float4 e2 = *(const float4*)(ea + (long)p2.x * KH + li * 4);
            float4 e3 = *(const float4*)(ea + (long)p3.x * KH + li * 4);
            float4 x0 = *(const float4*)(src + (long)p0.y * KH + li * 4);
            float4 x1 = *(const float4*)(src + (long)p1.y * KH + li * 4);
            float4 x2 = *(const float4*)(src + (long)p2.y * KH + li * 4);
            float4 x3 = *(const float4*)(src + (long)p3.y * KH + li * 4);
            float4 es4[4] = {e0, e1, e2, e3};
            float4 xs[4] = {x0, x1, x2, x3};
            #pragma unroll
            for (int u = 0; u < 4; ++u) {
                float m = (i + u <= last) ? 1.0f : 0.0f;
                acc.x = fmaf(m, fmaxf(xs[u].x + es4[u].x, 0.f), acc.x);
                acc.y = fmaf(m, fmaxf(xs[u].y + es4[u].y, 0.f), acc.y);
                acc.z = fmaf(m, fmaxf(xs[u].z + es4[u].z, 0.f), acc.z);
                acc.w = fmaf(m, fmaxf(xs[u].w + es4[u].w, 0.f), acc.w);
            }
        }
    }

    float4 r;
    r.x = fmaf(scale, dv.x, acc.x);
    r.y = fmaf(scale, dv.y, acc.y);
    r.z = fmaf(scale, dv.z, acc.z);
    r.w = fmaf(scale, dv.w, acc.w);

    unsigned short h0 = (unsigned short)bf16rn(r.x);
    unsigned short h1 = (unsigned short)bf16rn(r.y);
    unsigned short h2 = (unsigned short)bf16rn(r.z);
    unsigned short h3 = (unsigned short)bf16rn(r.w);
    unsigned short l0 = (unsigned short)bf16rn(r.x - bf16tof((short)h0));
    unsigned short l1 = (unsigned short)bf16rn(r.y - bf16tof((short)h1));
    unsigned short l2 = (unsigned short)bf16rn(r.z - bf16tof((short)h2));
    unsigned short l3 = (unsigned short)bf16rn(r.w - bf16tof((short)h3));
    long o = ((long)z * KN + node) * KH + li * 4;
    *(uint2*)(agg_hi + o) = make_uint2(((unsigned)h1 << 16) | h0, ((unsigned)h3 << 16) | h2);
    *(uint2*)(agg_lo + o) = make_uint2(((unsigned)l1 << 16) | l0, ((unsigned)l3 << 16) | l2);
}

// ---------------------------------------------------------------------------
// W pre-split: wsp[((mat*2+h)*4 + kc)*4096 + col*32 + kk], k = kc*32+kk.
// mat = arr*8 + (t*2+l), arr: 0=w1_ad 1=w1_da 2=w2_ad 3=w2_da.
// ---------------------------------------------------------------------------
__global__ __launch_bounds__(256)
void wsplit_k(const float* __restrict__ w1_ad, const float* __restrict__ w1_da,
              const float* __restrict__ w2_ad, const float* __restrict__ w2_da,
              short* __restrict__ wsp) {
    int mat = blockIdx.x >> 3, part = blockIdx.x & 7;   // mat 0..31
    int arr = mat >> 3, rem = mat & 7;   // rem = t*2+l
    const float* src = (arr == 0 ? w1_ad : arr == 1 ? w1_da : arr == 2 ? w2_ad : w2_da)
                       + (long)rem * KH * KH;
    #pragma unroll
    for (int p = 0; p < 8; ++p) {
        int idx = part * 2048 + p * 256 + threadIdx.x;  // 16384 elems total
        int k = idx >> 7, c = idx & 127;
        float v = src[idx];
        short hi = bf16rn(v);
        short lo = bf16rn(v - bf16tof(hi));
        int chunk = k >> 5, kk = k & 31;
        long ohi = ((long)(mat * 2 + 0) * 4 + chunk) * 4096 + c * 32 + kk;
        long olo = ((long)(mat * 2 + 1) * 4 + chunk) * 4096 + c * 32 + kk;
        wsp[ohi] = hi;
        wsp[olo] = lo;
    }
}

// ---------------------------------------------------------------------------
// Fused 2-layer MLP (3-term bf16-split MFMA, operand-swapped):
//   phase 1: mid = relu(agg @ W1 + b1)  -- A from global bf16 hi/lo,
//            result handed through LDS (bf16 hi/lo, [128][132] padded)
//   phase 2: out = [relu](mid @ W2 + b2) -> d_out fp32 (relu when l==0)
// Block: 128 nodes x 128 cols, 4 waves each 64x64.  Saves the mid HBM
// round-trip (82 MB write + 82 MB read per layer) and 2 launches.
// ---------------------------------------------------------------------------
__global__ __launch_bounds__(256)
void fused_k(const short* __restrict__ agg_hi, const short* __restrict__ agg_lo,
             const short* __restrict__ wsp,
             const float* __restrict__ b1_ad, const float* __restrict__ b1_da,
             const float* __restrict__ b2_ad, const float* __restrict__ b2_da,
             float* __restrict__ d_out, int l) {
    __shared__ short midh[128][132];
    __shared__ short midl[128][132];

    int z = blockIdx.y, t = z >> 1, et = z & 1;
    int tid = threadIdx.x;
    int mat1 = (0 * 2 + et) * 8 + t * 2 + l;
    int mat2 = (1 * 2 + et) * 8 + t * 2 + l;
    const float* Bp1 = (et ? b1_da : b1_ad) + (long)(t * KL + l) * KH;
    const float* Bp2 = (et ? b2_da : b2_ad) + (long)(t * KL + l) * KH;
    int r0 = blockIdx.x * 128;

    int lane = tid & 63, wid = tid >> 6;
    int wr = wid >> 1, wc = wid & 1;
    int lrow = lane & 15, lq = lane >> 4;

    f32x4 acc[4][4];
    #pragma unroll
    for (int i = 0; i < 4; ++i)
        #pragma unroll
        for (int j = 0; j < 4; ++j) acc[i][j] = (f32x4){0.f, 0.f, 0.f, 0.f};

    // ---- phase 1: acc = agg @ W1 (A rows from global bf16 hi/lo) ----
    #pragma unroll
    for (int kc = 0; kc < 4; ++kc) {
        const short* whp = wsp + ((long)(mat1 * 2 + 0) * 4 + kc) * 4096;
        const short* wlp = wsp + ((long)(mat1 * 2 + 1) * 4 + kc) * 4096;
        short8v bhi[4], blo[4];
        #pragma unroll
        for (int j = 0; j < 4; ++j) {
            int off = (wc * 64 + j * 16 + lrow) * 32 + lq * 8;
            bhi[j] = *(const short8v*)(whp + off);
            blo[j] = *(const short8v*)(wlp + off);
        }
        #pragma unroll
        for (int i = 0; i < 4; ++i) {
            int row = min(r0 + wr * 64 + i * 16 + lrow, KN - 1);
            long o = ((long)z * KN + row) * KH + kc * 32 + lq * 8;
            short8v ahi = *(const short8v*)(agg_hi + o);
            short8v alo = *(const short8v*)(agg_lo + o);
            #pragma unroll
            for (int j = 0; j < 4; ++j) {
                acc[i][j] = __builtin_amdgcn_mfma_f32_16x16x32_bf16(bhi[j], ahi, acc[i][j], 0, 0, 0);
                acc[i][j] = __builtin_amdgcn_mfma_f32_16x16x32_bf16(blo[j], ahi, acc[i][j], 0, 0, 0);
                acc[i][j] = __builtin_amdgcn_mfma_f32_16x16x32_bf16(bhi[j], alo, acc[i][j], 0, 0, 0);
            }
        }
    }

    // ---- epilogue 1: bias + relu, split to bf16 hi/lo, stash in LDS ----
    #pragma unroll
    for (int i = 0; i < 4; ++i) {
        int lr = wr * 64 + i * 16 + lrow;      // LDS row (always written)
        #pragma unroll
        for (int j = 0; j < 4; ++j) {
            int col = wc * 64 + j * 16 + lq * 4;
            float4 b4 = *(const float4*)&Bp1[col];
            f32x4 a = acc[i][j];
            float v0 = fmaxf(a[0] + b4.x, 0.f);
            float v1 = fmaxf(a[1] + b4.y, 0.f);
            float v2 = fmaxf(a[2] + b4.z, 0.f);
            float v3 = fmaxf(a[3] + b4.w, 0.f);
            unsigned short h0 = (unsigned short)bf16rn(v0);
            unsigned short h1 = (unsigned short)bf16rn(v1);
            unsigned short h2 = (unsigned short)bf16rn(v2);
            unsigned short h3 = (unsigned short)bf16rn(v3);
            unsigned short q0 = (unsigned short)bf16rn(v0 - bf16tof((short)h0));
            unsigned short q1 = (unsigned short)bf16rn(v1 - bf16tof((short)h1));
            unsigned short q2 = (unsigned short)bf16rn(v2 - bf16tof((short)h2));
            unsigned short q3 = (unsigned short)bf16rn(v3 - bf16tof((short)h3));
            *(uint2*)&midh[lr][col] = make_uint2(((unsigned)h1 << 16) | h0,
                                                 ((unsigned)h3 << 16) | h2);
            *(uint2*)&midl[lr][col] = make_uint2(((unsigned)q1 << 16) | q0,
                                                 ((unsigned)q3 << 16) | q2);
        }
    }
    __syncthreads();

    // ---- phase 2: acc = mid @ W2 (A from LDS, b64 reads on padded rows) ----
    #pragma unroll
    for (int i = 0; i < 4; ++i)
        #pragma unroll
        for (int j = 0; j < 4; ++j) acc[i][j] = (f32x4){0.f, 0.f, 0.f, 0.f};

    #pragma unroll
    for (int kc = 0; kc < 4; ++kc) {
        const short* whp = wsp + ((long)(mat2 * 2 + 0) * 4 + kc) * 4096;
        const short* wlp = wsp + ((long)(mat2 * 2 + 1) * 4 + kc) * 4096;
        short8v bhi[4], blo[4];
        #pragma unroll
        for (int j = 0; j < 4; ++j) {
            int off = (wc * 64 + j * 16 + lrow) * 32 + lq * 8;
            bhi[j] = *(const short8v*)(whp + off);
            blo[j] = *(const short8v*)(wlp + off);
        }
        #pragma unroll
        for (int i = 0; i < 4; ++i) {
            int lr = wr * 64 + i * 16 + lrow;
            int co = kc * 32 + lq * 8;
            uint2 ha = *(const uint2*)&midh[lr][co];
            uint2 hb = *(const uint2*)&midh[lr][co + 4];
            uint2 la = *(const uint2*)&midl[lr][co];
            uint2 lb = *(const uint2*)&midl[lr][co + 4];
            short8v ahi = mk8(ha, hb);
            short8v alo = mk8(la, lb);
            #pragma unroll
            for (int j = 0; j < 4; ++j) {
                acc[i][j] = __builtin_amdgcn_mfma_f32_16x16x32_bf16(bhi[j], ahi, acc[i][j], 0, 0, 0);
                acc[i][j] = __builtin_amdgcn_mfma_f32_16x16x32_bf16(blo[j], ahi, acc[i][j], 0, 0, 0);
                acc[i][j] = __builtin_amdgcn_mfma_f32_16x16x32_bf16(bhi[j], alo, acc[i][j], 0, 0, 0);
            }
        }
    }

    // ---- epilogue 2: bias (+relu between layers), fp32 to d_out ----
    int relu = (l == 0) ? 1 : 0;
    #pragma unroll
    for (int i = 0; i < 4; ++i) {
        int node = r0 + wr * 64 + i * 16 + lrow;
        if (node >= KN) continue;
        #pragma unroll
        for (int j = 0; j < 4; ++j) {
            int col = wc * 64 + j * 16 + lq * 4;
            float4 b4 = *(const float4*)&Bp2[col];
            f32x4 a = acc[i][j];
            float4 v;
            v.x = a[0] + b4.x; v.y = a[1] + b4.y;
            v.z = a[2] + b4.z; v.w = a[3] + b4.w;
            if (relu) {
                v.x = fmaxf(v.x, 0.f); v.y = fmaxf(v.y, 0.f);
                v.z = fmaxf(v.z, 0.f); v.w = fmaxf(v.w, 0.f);
            }
            long off = (long)t * KNT * KH + (et == 0 ? (long)KN * KH : 0)
                     + (long)node * KH + col;
            *(float4*)&d_out[off] = v;
        }
    }
}

// ---------------------------------------------------------------------------
extern "C" void kernel_launch(void* const* d_in, const int* in_sizes, int n_in,
                              void* d_out_v, int out_size, void* d_ws, size_t ws_size,
                              hipStream_t stream) {
    const float* x_a    = (const float*)d_in[0];
    const float* x_d    = (const float*)d_in[1];
    const float* ea_ad  = (const float*)d_in[2];
    const float* ea_da  = (const float*)d_in[3];
    const int*   ei_ad  = (const int*)d_in[4];
    const int*   ei_da  = (const int*)d_in[5];
    const float* w1_ad  = (const float*)d_in[6];
    const float* b1_ad  = (const float*)d_in[7];
    const float* w2_ad  = (const float*)d_in[8];
    const float* b2_ad  = (const float*)d_in[9];
    const float* eps_ad = (const float*)d_in[10];
    const float* w1_da  = (const float*)d_in[11];
    const float* b1_da  = (const float*)d_in[12];
    const float* w2_da  = (const float*)d_in[13];
    const float* b2_da  = (const float*)d_in[14];
    const float* eps_da = (const float*)d_in[15];
    float* out = (float*)d_out_v;

    // workspace layout: agg_hi | agg_lo | offs | cur | pes | wsp  (~90 MB)
    size_t nEl = (size_t)8 * KN * KH;
    short* agg_hi = (short*)d_ws;
    short* agg_lo = agg_hi + nEl;
    int*   offs   = (int*)(agg_lo + nEl);
    int*   cur    = offs + (size_t)8 * (KN + 1);
    int2*  pes    = (int2*)(cur + (size_t)8 * KN);
    short* wsp    = (short*)(pes + (size_t)8 * KE);       // 1,048,576 shorts

    hipMemsetAsync(cur, 0, (size_t)8 * KN * sizeof(int), stream);
    wsplit_k<<<256, 256, 0, stream>>>(w1_ad, w1_da, w2_ad, w2_da, wsp);

    dim3 eg((KE + 255) / 256, 8);
    count_k<<<eg, 256, 0, stream>>>(ei_ad, ei_da, cur);
    scan_k<<<8, 256, 0, stream>>>(cur, offs);
    fill_k<<<eg, 256, 0, stream>>>(ei_ad, ei_da, cur, pes);

    dim3 ag(KN / 8, 8);                  // 2500 x 8, exact
    dim3 gg((KN + 127) / 128, 8);        // 157 x 8

    for (int l = 0; l < KL; ++l) {
        const float* xab; long xats;
        const float* xdb; long xdts;
        if (l == 0) {
            xab = x_a; xats = (long)KN * KH;
            xdb = x_d; xdts = (long)KN * KH;
        } else {
            xab = out;                 xats = (long)KNT * KH;
            xdb = out + (long)KN * KH; xdts = (long)KNT * KH;
        }
        agg_k<<<ag, 256, 0, stream>>>(xab, xats, xdb, xdts,
                                      ea_ad, ea_da, eps_ad, eps_da,
                                      offs, pes, agg_hi, agg_lo, l);
        fused_k<<<gg, 256, 0, stream>>>(agg_hi, agg_lo, wsp,
                                        b1_ad, b1_da, b2_ad, b2_da, out, l);
    }
}